// Round 8
// baseline (368.866 us; speedup 1.0000x reference)
//
#include <hip/hip_runtime.h>
#include <cstdint>

#define NFEAT 128
#define CHUNK 4096
#define MAXBUCK 392
#define NPLANE 8
#define PFEAT 16

typedef _Float16 half8 __attribute__((ext_vector_type(8)));
typedef float f32x4 __attribute__((ext_vector_type(4)));

// ---------------- fused zero: cnt[N] + bfill[nbuck] ----------------

__global__ void zero2_k(int* __restrict__ a, int na, int* __restrict__ b, int nb) {
    int i = blockIdx.x * blockDim.x + threadIdx.x;
    if (i < na) a[i] = 0;
    else if (i < na + nb) b[i - na] = 0;
}

__global__ void hist_k(const int* __restrict__ dst, int E, int* __restrict__ cnt) {
    int stride = gridDim.x * blockDim.x;
    for (int e = blockIdx.x * blockDim.x + threadIdx.x; e < E; e += stride)
        atomicAdd(&cnt[dst[e]], 1);
}

// ---------------- scan (block phase also emits dinv) ----------------

__global__ void scan_block_k(const int* __restrict__ cnt, int* __restrict__ outv,
                             int* __restrict__ bsum, float* __restrict__ dinv, int N) {
    __shared__ int s[256];
    int i = blockIdx.x * 256 + threadIdx.x;
    int v = (i < N) ? cnt[i] : 0;
    if (i < N) dinv[i] = rsqrtf((float)(1 + v));
    s[threadIdx.x] = v;
    __syncthreads();
    for (int off = 1; off < 256; off <<= 1) {
        int t = (threadIdx.x >= off) ? s[threadIdx.x - off] : 0;
        __syncthreads();
        s[threadIdx.x] += t;
        __syncthreads();
    }
    if (i < N) outv[i] = s[threadIdx.x] - v;
    if (threadIdx.x == 255) bsum[blockIdx.x] = s[255];
}

__global__ void scan_top_k(int* __restrict__ bsum, int nb) {
    __shared__ int s[512];
    int v = (threadIdx.x < nb) ? bsum[threadIdx.x] : 0;
    s[threadIdx.x] = v;
    __syncthreads();
    for (int off = 1; off < 512; off <<= 1) {
        int t = (threadIdx.x >= off) ? s[threadIdx.x - off] : 0;
        __syncthreads();
        s[threadIdx.x] += t;
        __syncthreads();
    }
    if (threadIdx.x < nb) bsum[threadIdx.x] = s[threadIdx.x] - v;
}

__global__ void scan_add_k(int* __restrict__ rowptr, const int* __restrict__ bsum,
                           int N, int E) {
    int i = blockIdx.x * 256 + threadIdx.x;
    if (i < N) rowptr[i] += bsum[blockIdx.x];
    if (i == 0) rowptr[N] = E;
}

// ---------------- binned CSR build ----------------

__global__ __launch_bounds__(256) void binA2_k(const int* __restrict__ src,
                                               const int* __restrict__ dst,
                                               const int* __restrict__ rowptr,
                                               int* __restrict__ bfill,
                                               unsigned* __restrict__ binned,
                                               int E, int nbuck) {
    __shared__ int lhist[MAXBUCK];
    __shared__ int lbase[MAXBUCK];
    int e0 = blockIdx.x * CHUNK;
    int e1 = min(e0 + CHUNK, E);
    for (int i = threadIdx.x; i < nbuck; i += 256) lhist[i] = 0;
    __syncthreads();
    for (int e = e0 + threadIdx.x; e < e1; e += 256)
        atomicAdd(&lhist[dst[e] >> 8], 1);
    __syncthreads();
    for (int b = threadIdx.x; b < nbuck; b += 256) {
        int c = lhist[b];
        if (c > 0) lbase[b] = rowptr[b << 8] + atomicAdd(&bfill[b], c);
        lhist[b] = 0;
    }
    __syncthreads();
    for (int e = e0 + threadIdx.x; e < e1; e += 256) {
        int d = dst[e], s = src[e];
        int b = d >> 8;
        int r = atomicAdd(&lhist[b], 1);
        binned[lbase[b] + r] = ((unsigned)s << 8) | (unsigned)(d & 255);
    }
}

__global__ __launch_bounds__(256) void binB_k(const unsigned* __restrict__ binned,
                                              const int* __restrict__ rowptr,
                                              int* __restrict__ csr_src, int N) {
    __shared__ int rp[257];
    __shared__ int fill[256];
    __shared__ int stage[8192];
    int b = blockIdx.x;
    int n0 = b << 8;
    int nn = min(256, N - n0);
    for (int i = threadIdx.x; i <= nn; i += 256) rp[i] = rowptr[n0 + i];
    for (int i = threadIdx.x; i < 256; i += 256) fill[i] = 0;
    __syncthreads();
    int base = rp[0];
    int cnt = rp[nn] - base;
    for (int i = threadIdx.x; i < cnt; i += 256) {
        unsigned p = binned[base + i];
        int dl = (int)(p & 255u);
        int s = (int)(p >> 8);
        int pos = (rp[dl] - base) + atomicAdd(&fill[dl], 1);
        if (pos < 8192) stage[pos] = s;
        else csr_src[base + pos] = s;
    }
    __syncthreads();
    int m = cnt < 8192 ? cnt : 8192;
    for (int i = threadIdx.x; i < m; i += 256) csr_src[base + i] = stage[i];
}

// both weight transposes in one launch: W [k][n] fp32 -> WT [n][k] f16
__global__ void wtrans2_k(const float* __restrict__ W1, const float* __restrict__ W2,
                          _Float16* __restrict__ WT1, _Float16* __restrict__ WT2) {
    int idx = blockIdx.x * 256 + threadIdx.x;  // 128 blocks
    const float* W = (idx < 16384) ? W1 : W2;
    _Float16* WT = (idx < 16384) ? WT1 : WT2;
    int i = idx & 16383;
    int n = i >> 7, k = i & 127;
    WT[i] = (_Float16)W[k * NFEAT + n];
}

// ---------------- MFMA f16 GEMM: Hp = (X @ W) * dinv[row], PLANE-MAJOR out ----
// Hp[p][row][16] f16. 128-row tile, full K=128 single stage, 4 waves 64x64 each.

template <bool SRC_F16>
__global__ __launch_bounds__(256) void gemm_mfma_k(const void* __restrict__ Xv,
                                                   const _Float16* __restrict__ WT,
                                                   const float* __restrict__ dinvp,
                                                   _Float16* __restrict__ Hp, int nrows) {
    __shared__ uint4 ldsbuf[4096];  // 64 KB
    char* ldsA = (char*)ldsbuf;
    char* ldsB = (char*)ldsbuf + 32768;
    const int t = threadIdx.x;
    const int row0 = blockIdx.x * 128;

#pragma unroll
    for (int i = 0; i < 8; ++i) {
        int chunk = i * 256 + t;
        int r = chunk >> 4, cb = chunk & 15;
        half8 hv;
        if (row0 + r < nrows) {
            if (SRC_F16) {
                hv = *(const half8*)((const _Float16*)Xv + (size_t)(row0 + r) * NFEAT + cb * 8);
            } else {
                const float* X = (const float*)Xv;
                float4 v0 = *(const float4*)(X + (size_t)(row0 + r) * NFEAT + cb * 8);
                float4 v1 = *(const float4*)(X + (size_t)(row0 + r) * NFEAT + cb * 8 + 4);
                hv[0] = (_Float16)v0.x; hv[1] = (_Float16)v0.y;
                hv[2] = (_Float16)v0.z; hv[3] = (_Float16)v0.w;
                hv[4] = (_Float16)v1.x; hv[5] = (_Float16)v1.y;
                hv[6] = (_Float16)v1.z; hv[7] = (_Float16)v1.w;
            }
        } else {
            hv = (half8)(_Float16)0.f;
        }
        int byte = (r * 256 + cb * 16) ^ ((r & 7) << 4);
        *(half8*)(ldsA + byte) = hv;
    }
#pragma unroll
    for (int i = 0; i < 8; ++i) {
        int chunk = i * 256 + t;
        int r = chunk >> 4, cb = chunk & 15;
        half8 hv = *(const half8*)(WT + (size_t)r * NFEAT + cb * 8);
        int byte = (r * 256 + cb * 16) ^ ((r & 7) << 4);
        *(half8*)(ldsB + byte) = hv;
    }
    __syncthreads();

    const int w = t >> 6, lane = t & 63;
    const int wr = w >> 1, wc = w & 1;
    const int lrow = lane & 15, kgrp = lane >> 4;

    f32x4 acc[4][4];
#pragma unroll
    for (int m = 0; m < 4; ++m)
#pragma unroll
        for (int n = 0; n < 4; ++n) acc[m][n] = (f32x4)0.f;

#pragma unroll
    for (int kk = 0; kk < 4; ++kk) {
        int kb = (kk * 32 + kgrp * 8) * 2;
        half8 a[4], b[4];
#pragma unroll
        for (int m = 0; m < 4; ++m) {
            int r = wr * 64 + m * 16 + lrow;
            a[m] = *(const half8*)(ldsA + ((r * 256 + kb) ^ ((r & 7) << 4)));
        }
#pragma unroll
        for (int n = 0; n < 4; ++n) {
            int c = wc * 64 + n * 16 + lrow;
            b[n] = *(const half8*)(ldsB + ((c * 256 + kb) ^ ((c & 7) << 4)));
        }
#pragma unroll
        for (int m = 0; m < 4; ++m)
#pragma unroll
            for (int n = 0; n < 4; ++n)
                acc[m][n] = __builtin_amdgcn_mfma_f32_16x16x32_f16(a[m], b[n], acc[m][n], 0, 0, 0);
    }

    // epilogue: plane-major. feature = wc*64+n*16+lrow -> plane = wc*4+n, feat = lrow
#pragma unroll
    for (int m = 0; m < 4; ++m) {
#pragma unroll
        for (int j = 0; j < 4; ++j) {
            int row = row0 + wr * 64 + m * 16 + kgrp * 4 + j;
            if (row < nrows) {
                float sc = dinvp[row];
#pragma unroll
                for (int n = 0; n < 4; ++n) {
                    int plane = wc * 4 + n;
                    Hp[((size_t)plane * nrows + row) * PFEAT + lrow] =
                        (_Float16)(acc[m][n][j] * sc);
                }
            }
        }
    }
}

// ---------------- plane-sharded CSR aggregation, wide loads ----------------
// blockIdx&7 = plane -> XCD (round-robin): per-XCD gather set = 3.2MB plane (L2-fit).
// Wave = 4 nodes x 8 edge-groups x 2 feature-halves; each lane gathers half8 (16B).
// One vmem instr = 32 edge-halves = 512B from L2-resident plane.

template <bool FINAL>
__global__ __launch_bounds__(256) void agg_plane_k(const int* __restrict__ rowptr,
                                                   const int* __restrict__ csr_src,
                                                   const float* __restrict__ dinv,
                                                   const _Float16* __restrict__ hp,
                                                   const float* __restrict__ bias,
                                                   void* __restrict__ outv, int N) {
    int plane = blockIdx.x & 7;
    int nblk = blockIdx.x >> 3;
    int t = threadIdx.x;
    int wave = t >> 6, lane = t & 63;
    int ns = lane >> 4;        // node slot 0..3
    int g = (lane >> 1) & 7;   // edge group 0..7
    int fl = lane & 1;         // feature half: feats fl*8..fl*8+7 of the plane
    int node = nblk * 16 + wave * 4 + ns;
    if (node >= N) return;

    const _Float16* hb = hp + (size_t)plane * N * PFEAT + fl * 8;
    int p1 = rowptr[node + 1];
    int p = rowptr[node] + g;
    float acc[8] = {0.f, 0.f, 0.f, 0.f, 0.f, 0.f, 0.f, 0.f};

    while (__any(p < p1)) {
        if (p < p1) {
            int s = csr_src[p];
            half8 v = *(const half8*)(hb + (size_t)s * PFEAT);
#pragma unroll
            for (int i = 0; i < 8; ++i) acc[i] += (float)v[i];
        }
        p += 8;
    }
    if (g == 0) {  // self-loop once
        half8 vs = *(const half8*)(hb + (size_t)node * PFEAT);
#pragma unroll
        for (int i = 0; i < 8; ++i) acc[i] += (float)vs[i];
    }
    // reduce across the 8 edge groups (lane bits 1..3), preserving fl (bit 0)
#pragma unroll
    for (int i = 0; i < 8; ++i) {
        acc[i] += __shfl_xor(acc[i], 2, 64);
        acc[i] += __shfl_xor(acc[i], 4, 64);
        acc[i] += __shfl_xor(acc[i], 8, 64);
    }
    if (g == 0) {
        float dd = dinv[node];
        const float* bp = bias + plane * PFEAT + fl * 8;
        float4 bv0 = *(const float4*)bp;
        float4 bv1 = *(const float4*)(bp + 4);
        float o[8];
        o[0] = fmaf(dd, acc[0], bv0.x); o[1] = fmaf(dd, acc[1], bv0.y);
        o[2] = fmaf(dd, acc[2], bv0.z); o[3] = fmaf(dd, acc[3], bv0.w);
        o[4] = fmaf(dd, acc[4], bv1.x); o[5] = fmaf(dd, acc[5], bv1.y);
        o[6] = fmaf(dd, acc[6], bv1.z); o[7] = fmaf(dd, acc[7], bv1.w);
        if (FINAL) {
            float* out = (float*)outv + (size_t)node * NFEAT + plane * PFEAT + fl * 8;
            *(float4*)out = make_float4(o[0], o[1], o[2], o[3]);
            *(float4*)(out + 4) = make_float4(o[4], o[5], o[6], o[7]);
        } else {
            half8 ho;
#pragma unroll
            for (int i = 0; i < 8; ++i) ho[i] = (_Float16)fmaxf(o[i], 0.f);
            *(half8*)((_Float16*)outv + (size_t)node * NFEAT + plane * PFEAT + fl * 8) = ho;
        }
    }
}

// ---------------- launch ----------------

extern "C" void kernel_launch(void* const* d_in, const int* in_sizes, int n_in,
                              void* d_out, int out_size, void* d_ws, size_t ws_size,
                              hipStream_t stream) {
    const float* x  = (const float*)d_in[0];
    const int*   ei = (const int*)d_in[1];
    const float* W1 = (const float*)d_in[2];
    const float* b1 = (const float*)d_in[3];
    const float* W2 = (const float*)d_in[4];
    const float* b2 = (const float*)d_in[5];
    float* out = (float*)d_out;

    const int N = in_sizes[0] / NFEAT;
    const int E = in_sizes[1] / 2;
    const int* srcv = ei;
    const int* dstv = ei + E;

    char* wsp = (char*)d_ws;
    size_t off = 0;
    auto alloc = [&](size_t bytes) {
        char* p = wsp + off;
        off = (off + bytes + 255) & ~(size_t)255;
        return p;
    };
    float*    dinv    = (float*)alloc((size_t)N * 4);
    int*      rowptr  = (int*)alloc((size_t)(N + 1) * 4);
    int*      bsum    = (int*)alloc(512 * 4);
    int*      cnt     = (int*)alloc((size_t)N * 4);
    int*      bfill   = (int*)alloc(MAXBUCK * 4);
    int*      csr_src = (int*)alloc((size_t)E * 4);
    _Float16* wt1     = (_Float16*)alloc(NFEAT * NFEAT * 2);
    _Float16* wt2     = (_Float16*)alloc(NFEAT * NFEAT * 2);
    _Float16* hbuf    = (_Float16*)alloc((size_t)N * NFEAT * 2);  // plane-major [8][N][16]
    _Float16* a1buf   = (_Float16*)alloc((size_t)N * NFEAT * 2);  // row-major
    unsigned* binned  = (unsigned*)hbuf;  // alias: consumed by binB before gemm1

    const int nb = (N + 255) / 256;
    const int nbuck = (N + 255) >> 8;

    // build: degree + dinv + rowptr + binned CSR
    zero2_k<<<(N + nbuck + 255) / 256, 256, 0, stream>>>(cnt, N, bfill, nbuck);
    hist_k<<<2048, 256, 0, stream>>>(dstv, E, cnt);
    scan_block_k<<<nb, 256, 0, stream>>>(cnt, rowptr, bsum, dinv, N);
    scan_top_k<<<1, 512, 0, stream>>>(bsum, nb);
    scan_add_k<<<nb, 256, 0, stream>>>(rowptr, bsum, N, E);
    binA2_k<<<(E + CHUNK - 1) / CHUNK, 256, 0, stream>>>(srcv, dstv, rowptr, bfill, binned, E, nbuck);
    binB_k<<<nbuck, 256, 0, stream>>>(binned, rowptr, csr_src, N);
    wtrans2_k<<<128, 256, 0, stream>>>(W1, W2, wt1, wt2);

    const int gemm_blocks = (N + 127) / 128;
    const int agg_blocks = NPLANE * ((N + 15) / 16);

    // layer 1: h1' = (x@W1)*dinv (plane-major) ; a1 = relu(dinv*Agg(h1') + b1) (row-major f16)
    gemm_mfma_k<false><<<gemm_blocks, 256, 0, stream>>>(x, wt1, dinv, hbuf, N);
    agg_plane_k<false><<<agg_blocks, 256, 0, stream>>>(rowptr, csr_src, dinv, hbuf, b1, a1buf, N);

    // layer 2: h2' = (a1@W2)*dinv (plane-major) ; out = dinv*Agg(h2') + b2 (fp32)
    gemm_mfma_k<true><<<gemm_blocks, 256, 0, stream>>>(a1buf, wt2, dinv, hbuf, N);
    agg_plane_k<true><<<agg_blocks, 256, 0, stream>>>(rowptr, csr_src, dinv, hbuf, b2, out, N);
}

// Round 9
// 284.827 us; speedup vs baseline: 1.2951x; 1.2951x over previous
//
#include <hip/hip_runtime.h>
#include <cstdint>

#define NFEAT 128
#define CHUNK 4096
#define MAXBUCK 392

typedef _Float16 half8 __attribute__((ext_vector_type(8)));
typedef float f32x4 __attribute__((ext_vector_type(4)));

// ---------------- prep: zero cnt/bfill + both weight transposes ----------------

__global__ void prep_k(int* __restrict__ cnt, int N, int* __restrict__ bfill, int nbuck,
                       const float* __restrict__ W1, const float* __restrict__ W2,
                       _Float16* __restrict__ WT1, _Float16* __restrict__ WT2) {
    int i = blockIdx.x * blockDim.x + threadIdx.x;
    if (i < N) cnt[i] = 0;
    else if (i < N + nbuck) bfill[i - N] = 0;
    if (i < 16384) {
        int n = i >> 7, k = i & 127;
        WT1[i] = (_Float16)W1[k * NFEAT + n];
        WT2[i] = (_Float16)W2[k * NFEAT + n];
    }
}

__global__ void hist_k(const int* __restrict__ dst, int E, int* __restrict__ cnt) {
    int stride = gridDim.x * blockDim.x;
    for (int e = blockIdx.x * blockDim.x + threadIdx.x; e < E; e += stride)
        atomicAdd(&cnt[dst[e]], 1);
}

// ---------------- scan (block phase also emits dinv) ----------------

__global__ void scan_block_k(const int* __restrict__ cnt, int* __restrict__ outv,
                             int* __restrict__ bsum, float* __restrict__ dinv, int N) {
    __shared__ int s[256];
    int i = blockIdx.x * 256 + threadIdx.x;
    int v = (i < N) ? cnt[i] : 0;
    if (i < N) dinv[i] = rsqrtf((float)(1 + v));
    s[threadIdx.x] = v;
    __syncthreads();
    for (int off = 1; off < 256; off <<= 1) {
        int t = (threadIdx.x >= off) ? s[threadIdx.x - off] : 0;
        __syncthreads();
        s[threadIdx.x] += t;
        __syncthreads();
    }
    if (i < N) outv[i] = s[threadIdx.x] - v;
    if (threadIdx.x == 255) bsum[blockIdx.x] = s[255];
}

__global__ void scan_top_k(int* __restrict__ bsum, int nb) {
    __shared__ int s[512];
    int v = (threadIdx.x < nb) ? bsum[threadIdx.x] : 0;
    s[threadIdx.x] = v;
    __syncthreads();
    for (int off = 1; off < 512; off <<= 1) {
        int t = (threadIdx.x >= off) ? s[threadIdx.x - off] : 0;
        __syncthreads();
        s[threadIdx.x] += t;
        __syncthreads();
    }
    if (threadIdx.x < nb) bsum[threadIdx.x] = s[threadIdx.x] - v;
}

__global__ void scan_add_k(int* __restrict__ rowptr, const int* __restrict__ bsum,
                           int N, int E) {
    int i = blockIdx.x * 256 + threadIdx.x;
    if (i < N) rowptr[i] += bsum[blockIdx.x];
    if (i == 0) rowptr[N] = E;
}

// ---------------- binned CSR build ----------------

__global__ __launch_bounds__(256) void binA2_k(const int* __restrict__ src,
                                               const int* __restrict__ dst,
                                               const int* __restrict__ rowptr,
                                               int* __restrict__ bfill,
                                               unsigned* __restrict__ binned,
                                               int E, int nbuck) {
    __shared__ int lhist[MAXBUCK];
    __shared__ int lbase[MAXBUCK];
    int e0 = blockIdx.x * CHUNK;
    int e1 = min(e0 + CHUNK, E);
    for (int i = threadIdx.x; i < nbuck; i += 256) lhist[i] = 0;
    __syncthreads();
    for (int e = e0 + threadIdx.x; e < e1; e += 256)
        atomicAdd(&lhist[dst[e] >> 8], 1);
    __syncthreads();
    for (int b = threadIdx.x; b < nbuck; b += 256) {
        int c = lhist[b];
        if (c > 0) lbase[b] = rowptr[b << 8] + atomicAdd(&bfill[b], c);
        lhist[b] = 0;
    }
    __syncthreads();
    for (int e = e0 + threadIdx.x; e < e1; e += 256) {
        int d = dst[e], s = src[e];
        int b = d >> 8;
        int r = atomicAdd(&lhist[b], 1);
        binned[lbase[b] + r] = ((unsigned)s << 8) | (unsigned)(d & 255);
    }
}

__global__ __launch_bounds__(256) void binB_k(const unsigned* __restrict__ binned,
                                              const int* __restrict__ rowptr,
                                              int* __restrict__ csr_src, int N) {
    __shared__ int rp[257];
    __shared__ int fill[256];
    __shared__ int stage[8192];
    int b = blockIdx.x;
    int n0 = b << 8;
    int nn = min(256, N - n0);
    for (int i = threadIdx.x; i <= nn; i += 256) rp[i] = rowptr[n0 + i];
    for (int i = threadIdx.x; i < 256; i += 256) fill[i] = 0;
    __syncthreads();
    int base = rp[0];
    int cnt = rp[nn] - base;
    for (int i = threadIdx.x; i < cnt; i += 256) {
        unsigned p = binned[base + i];
        int dl = (int)(p & 255u);
        int s = (int)(p >> 8);
        int pos = (rp[dl] - base) + atomicAdd(&fill[dl], 1);
        if (pos < 8192) stage[pos] = s;
        else csr_src[base + pos] = s;
    }
    __syncthreads();
    int m = cnt < 8192 ? cnt : 8192;
    for (int i = threadIdx.x; i < m; i += 256) csr_src[base + i] = stage[i];
}

// ---------------- MFMA f16 GEMM: H = (X @ W) * dinv[row]  (f16 row-major out) ----

template <bool SRC_F16>
__global__ __launch_bounds__(256) void gemm_mfma_k(const void* __restrict__ Xv,
                                                   const _Float16* __restrict__ WT,
                                                   const float* __restrict__ dinvp,
                                                   _Float16* __restrict__ H, int nrows) {
    __shared__ uint4 ldsbuf[4096];  // 64 KB
    char* ldsA = (char*)ldsbuf;
    char* ldsB = (char*)ldsbuf + 32768;
    const int t = threadIdx.x;
    const int row0 = blockIdx.x * 128;

#pragma unroll
    for (int i = 0; i < 8; ++i) {
        int chunk = i * 256 + t;
        int r = chunk >> 4, cb = chunk & 15;
        half8 hv;
        if (row0 + r < nrows) {
            if (SRC_F16) {
                hv = *(const half8*)((const _Float16*)Xv + (size_t)(row0 + r) * NFEAT + cb * 8);
            } else {
                const float* X = (const float*)Xv;
                float4 v0 = *(const float4*)(X + (size_t)(row0 + r) * NFEAT + cb * 8);
                float4 v1 = *(const float4*)(X + (size_t)(row0 + r) * NFEAT + cb * 8 + 4);
                hv[0] = (_Float16)v0.x; hv[1] = (_Float16)v0.y;
                hv[2] = (_Float16)v0.z; hv[3] = (_Float16)v0.w;
                hv[4] = (_Float16)v1.x; hv[5] = (_Float16)v1.y;
                hv[6] = (_Float16)v1.z; hv[7] = (_Float16)v1.w;
            }
        } else {
            hv = (half8)(_Float16)0.f;
        }
        int byte = (r * 256 + cb * 16) ^ ((r & 7) << 4);
        *(half8*)(ldsA + byte) = hv;
    }
#pragma unroll
    for (int i = 0; i < 8; ++i) {
        int chunk = i * 256 + t;
        int r = chunk >> 4, cb = chunk & 15;
        half8 hv = *(const half8*)(WT + (size_t)r * NFEAT + cb * 8);
        int byte = (r * 256 + cb * 16) ^ ((r & 7) << 4);
        *(half8*)(ldsB + byte) = hv;
    }
    __syncthreads();

    const int w = t >> 6, lane = t & 63;
    const int wr = w >> 1, wc = w & 1;
    const int lrow = lane & 15, kgrp = lane >> 4;

    f32x4 acc[4][4];
#pragma unroll
    for (int m = 0; m < 4; ++m)
#pragma unroll
        for (int n = 0; n < 4; ++n) acc[m][n] = (f32x4)0.f;

#pragma unroll
    for (int kk = 0; kk < 4; ++kk) {
        int kb = (kk * 32 + kgrp * 8) * 2;
        half8 a[4], b[4];
#pragma unroll
        for (int m = 0; m < 4; ++m) {
            int r = wr * 64 + m * 16 + lrow;
            a[m] = *(const half8*)(ldsA + ((r * 256 + kb) ^ ((r & 7) << 4)));
        }
#pragma unroll
        for (int n = 0; n < 4; ++n) {
            int c = wc * 64 + n * 16 + lrow;
            b[n] = *(const half8*)(ldsB + ((c * 256 + kb) ^ ((c & 7) << 4)));
        }
#pragma unroll
        for (int m = 0; m < 4; ++m)
#pragma unroll
            for (int n = 0; n < 4; ++n)
                acc[m][n] = __builtin_amdgcn_mfma_f32_16x16x32_f16(a[m], b[n], acc[m][n], 0, 0, 0);
    }

#pragma unroll
    for (int m = 0; m < 4; ++m) {
#pragma unroll
        for (int j = 0; j < 4; ++j) {
            int row = row0 + wr * 64 + m * 16 + kgrp * 4 + j;
            if (row < nrows) {
                float sc = dinvp[row];
#pragma unroll
                for (int n = 0; n < 4; ++n)
                    H[(size_t)row * NFEAT + wc * 64 + n * 16 + lrow] =
                        (_Float16)(acc[m][n][j] * sc);
            }
        }
    }
}

// ---------------- CSR aggregation: one wave per node, 4 groups x 16 lanes ----
// 16-edge unroll: 4 half8 gathers (16B each) in flight per lane; packed f16
// accumulation (v_pk_add_f16) in 4 independent partials; f32 only at reduce.

template <bool FINAL>
__global__ __launch_bounds__(256) void agg_csr_k(const int* __restrict__ rowptr,
                                                 const int* __restrict__ csr_src,
                                                 const float* __restrict__ dinv,
                                                 const _Float16* __restrict__ h,
                                                 const float* __restrict__ bias,
                                                 void* __restrict__ outv, int N) {
    int node = (int)((blockIdx.x * (unsigned)blockDim.x + threadIdx.x) >> 6);
    if (node >= N) return;
    int lane = threadIdx.x & 63;
    int g = lane >> 4;        // edge group 0..3
    int fl = lane & 15;       // feature block: feats fl*8 .. fl*8+7
    const _Float16* hfb = h + fl * 8;

    int p0 = rowptr[node], p1 = rowptr[node + 1];
    half8 ha0 = (half8)(_Float16)0.f, ha1 = ha0, ha2 = ha0, ha3 = ha0;

    int p = p0;
    for (; p + 16 <= p1; p += 16) {
        int s0 = csr_src[p + g];
        int s1 = csr_src[p + 4 + g];
        int s2 = csr_src[p + 8 + g];
        int s3 = csr_src[p + 12 + g];
        half8 v0 = *(const half8*)(hfb + (size_t)s0 * NFEAT);
        half8 v1 = *(const half8*)(hfb + (size_t)s1 * NFEAT);
        half8 v2 = *(const half8*)(hfb + (size_t)s2 * NFEAT);
        half8 v3 = *(const half8*)(hfb + (size_t)s3 * NFEAT);
        ha0 += v0; ha1 += v1; ha2 += v2; ha3 += v3;
    }
    if (p + 8 <= p1) {
        int s0 = csr_src[p + g];
        int s1 = csr_src[p + 4 + g];
        half8 v0 = *(const half8*)(hfb + (size_t)s0 * NFEAT);
        half8 v1 = *(const half8*)(hfb + (size_t)s1 * NFEAT);
        ha0 += v0; ha1 += v1;
        p += 8;
    }
    if (p + 4 <= p1) {
        int s0 = csr_src[p + g];
        half8 v0 = *(const half8*)(hfb + (size_t)s0 * NFEAT);
        ha2 += v0;
        p += 4;
    }
    if (p + g < p1) {
        int s0 = csr_src[p + g];
        half8 v0 = *(const half8*)(hfb + (size_t)s0 * NFEAT);
        ha3 += v0;
    }
    if (g == 0) {  // self-loop once
        half8 vs = *(const half8*)(hfb + (size_t)node * NFEAT);
        ha0 += vs;
    }
    ha0 += ha1;
    ha2 += ha3;
    ha0 += ha2;

    float acc[8];
#pragma unroll
    for (int i = 0; i < 8; ++i) acc[i] = (float)ha0[i];
    // cross-group reduce (lanes l, l^16, l^32, l^48)
#pragma unroll
    for (int i = 0; i < 8; ++i) {
        acc[i] += __shfl_xor(acc[i], 16, 64);
        acc[i] += __shfl_xor(acc[i], 32, 64);
    }
    if (g == 0) {
        float dd = dinv[node];
        float4 bv0 = *(const float4*)(bias + fl * 8);
        float4 bv1 = *(const float4*)(bias + fl * 8 + 4);
        float o[8];
        o[0] = fmaf(dd, acc[0], bv0.x); o[1] = fmaf(dd, acc[1], bv0.y);
        o[2] = fmaf(dd, acc[2], bv0.z); o[3] = fmaf(dd, acc[3], bv0.w);
        o[4] = fmaf(dd, acc[4], bv1.x); o[5] = fmaf(dd, acc[5], bv1.y);
        o[6] = fmaf(dd, acc[6], bv1.z); o[7] = fmaf(dd, acc[7], bv1.w);
        if (FINAL) {
            float* out = (float*)outv + (size_t)node * NFEAT + fl * 8;
            *(float4*)out = make_float4(o[0], o[1], o[2], o[3]);
            *(float4*)(out + 4) = make_float4(o[4], o[5], o[6], o[7]);
        } else {
            half8 ho;
#pragma unroll
            for (int i = 0; i < 8; ++i) ho[i] = (_Float16)fmaxf(o[i], 0.f);
            *(half8*)((_Float16*)outv + (size_t)node * NFEAT + fl * 8) = ho;
        }
    }
}

// ---------------- launch ----------------

extern "C" void kernel_launch(void* const* d_in, const int* in_sizes, int n_in,
                              void* d_out, int out_size, void* d_ws, size_t ws_size,
                              hipStream_t stream) {
    const float* x  = (const float*)d_in[0];
    const int*   ei = (const int*)d_in[1];
    const float* W1 = (const float*)d_in[2];
    const float* b1 = (const float*)d_in[3];
    const float* W2 = (const float*)d_in[4];
    const float* b2 = (const float*)d_in[5];
    float* out = (float*)d_out;

    const int N = in_sizes[0] / NFEAT;
    const int E = in_sizes[1] / 2;
    const int* srcv = ei;
    const int* dstv = ei + E;

    char* wsp = (char*)d_ws;
    size_t off = 0;
    auto alloc = [&](size_t bytes) {
        char* p = wsp + off;
        off = (off + bytes + 255) & ~(size_t)255;
        return p;
    };
    float*    dinv    = (float*)alloc((size_t)N * 4);
    int*      rowptr  = (int*)alloc((size_t)(N + 1) * 4);
    int*      bsum    = (int*)alloc(512 * 4);
    int*      cnt     = (int*)alloc((size_t)N * 4);
    int*      bfill   = (int*)alloc(MAXBUCK * 4);
    int*      csr_src = (int*)alloc((size_t)E * 4);
    _Float16* wt1     = (_Float16*)alloc(NFEAT * NFEAT * 2);
    _Float16* wt2     = (_Float16*)alloc(NFEAT * NFEAT * 2);
    _Float16* hbuf    = (_Float16*)alloc((size_t)N * NFEAT * 2);
    _Float16* a1buf   = (_Float16*)alloc((size_t)N * NFEAT * 2);
    unsigned* binned  = (unsigned*)hbuf;  // alias: consumed by binB before gemm1

    const int nb = (N + 255) / 256;
    const int nbuck = (N + 255) >> 8;

    // build: prep (zero + wtrans) + degree/dinv + rowptr + binned CSR
    prep_k<<<(N + nbuck + 255) / 256, 256, 0, stream>>>(cnt, N, bfill, nbuck, W1, W2, wt1, wt2);
    hist_k<<<2048, 256, 0, stream>>>(dstv, E, cnt);
    scan_block_k<<<nb, 256, 0, stream>>>(cnt, rowptr, bsum, dinv, N);
    scan_top_k<<<1, 512, 0, stream>>>(bsum, nb);
    scan_add_k<<<nb, 256, 0, stream>>>(rowptr, bsum, N, E);
    binA2_k<<<(E + CHUNK - 1) / CHUNK, 256, 0, stream>>>(srcv, dstv, rowptr, bfill, binned, E, nbuck);
    binB_k<<<nbuck, 256, 0, stream>>>(binned, rowptr, csr_src, N);

    const int gemm_blocks = (N + 127) / 128;
    const int agg_blocks = (int)(((size_t)N * 64 + 255) / 256);

    // layer 1: h1' = (x@W1)*dinv ; a1 = relu(dinv*Agg(h1') + b1) (f16)
    gemm_mfma_k<false><<<gemm_blocks, 256, 0, stream>>>(x, wt1, dinv, hbuf, N);
    agg_csr_k<false><<<agg_blocks, 256, 0, stream>>>(rowptr, csr_src, dinv, hbuf, b1, a1buf, N);

    // layer 2: h2' = (a1@W2)*dinv ; out = dinv*Agg(h2') + b2 (fp32)
    gemm_mfma_k<true><<<gemm_blocks, 256, 0, stream>>>(a1buf, wt2, dinv, hbuf, N);
    agg_csr_k<true><<<agg_blocks, 256, 0, stream>>>(rowptr, csr_src, dinv, hbuf, b2, out, N);
}

// Round 10
// 226.510 us; speedup vs baseline: 1.6285x; 1.2575x over previous
//
#include <hip/hip_runtime.h>
#include <cstdint>

#define NFEAT 128
#define CHUNK 4096
#define MAXBUCK 392

typedef _Float16 half8 __attribute__((ext_vector_type(8)));
typedef float f32x4 __attribute__((ext_vector_type(4)));

// ---------------- prep: zero bucket counters + both weight transposes ----------------

__global__ void prep_k(int* __restrict__ gcount, int nbuck,
                       const float* __restrict__ W1, const float* __restrict__ W2,
                       _Float16* __restrict__ WT1, _Float16* __restrict__ WT2) {
    int i = blockIdx.x * blockDim.x + threadIdx.x;
    if (i < nbuck) gcount[i] = 0;
    if (i < 16384) {
        int n = i >> 7, k = i & 127;
        WT1[i] = (_Float16)W1[k * NFEAT + n];
        WT2[i] = (_Float16)W2[k * NFEAT + n];
    }
}

// ---------------- bucket histogram: LDS-staged, one global add per (chunk,bucket) ----

__global__ __launch_bounds__(256) void bhist_k(const int* __restrict__ dst, int E,
                                               int* __restrict__ gcount, int nbuck) {
    __shared__ int lh[MAXBUCK];
    int e0 = blockIdx.x * CHUNK;
    int e1 = min(e0 + CHUNK, E);
    for (int i = threadIdx.x; i < nbuck; i += 256) lh[i] = 0;
    __syncthreads();
    for (int e = e0 + threadIdx.x; e < e1; e += 256)
        atomicAdd(&lh[dst[e] >> 8], 1);
    __syncthreads();
    for (int b = threadIdx.x; b < nbuck; b += 256)
        if (lh[b] > 0) atomicAdd(&gcount[b], lh[b]);
}

// ---------------- bucket scan: 1 block; bucket_base = excl scan; zero bfill ----------

__global__ void bscan_k(const int* __restrict__ gcount, int* __restrict__ bucket_base,
                        int* __restrict__ bfill, int nbuck) {
    __shared__ int s[512];
    int t = threadIdx.x;
    int v = (t < nbuck) ? gcount[t] : 0;
    s[t] = v;
    __syncthreads();
    for (int off = 1; off < 512; off <<= 1) {
        int tv = (t >= off) ? s[t - off] : 0;
        __syncthreads();
        s[t] += tv;
        __syncthreads();
    }
    if (t < nbuck) {
        bucket_base[t] = s[t] - v;  // exclusive
        bfill[t] = 0;
    }
}

// ---------------- binA2: block-staged radix append into bucket regions ----------------

__global__ __launch_bounds__(256) void binA2_k(const int* __restrict__ src,
                                               const int* __restrict__ dst,
                                               const int* __restrict__ bucket_base,
                                               int* __restrict__ bfill,
                                               unsigned* __restrict__ binned,
                                               int E, int nbuck) {
    __shared__ int lhist[MAXBUCK];
    __shared__ int lbase[MAXBUCK];
    int e0 = blockIdx.x * CHUNK;
    int e1 = min(e0 + CHUNK, E);
    for (int i = threadIdx.x; i < nbuck; i += 256) lhist[i] = 0;
    __syncthreads();
    for (int e = e0 + threadIdx.x; e < e1; e += 256)
        atomicAdd(&lhist[dst[e] >> 8], 1);
    __syncthreads();
    for (int b = threadIdx.x; b < nbuck; b += 256) {
        int c = lhist[b];
        if (c > 0) lbase[b] = bucket_base[b] + atomicAdd(&bfill[b], c);
        lhist[b] = 0;
    }
    __syncthreads();
    for (int e = e0 + threadIdx.x; e < e1; e += 256) {
        int d = dst[e], s = src[e];
        int b = d >> 8;
        int r = atomicAdd(&lhist[b], 1);
        binned[lbase[b] + r] = ((unsigned)s << 8) | (unsigned)(d & 255);
    }
}

// ---------------- binB2: per-bucket counting sort; also emits rowptr + dinv -----------

__global__ __launch_bounds__(256) void binB2_k(const unsigned* __restrict__ binned,
                                               const int* __restrict__ bucket_base,
                                               int* __restrict__ rowptr,
                                               float* __restrict__ dinv,
                                               int* __restrict__ csr_src,
                                               int N, int E, int nbuck) {
    __shared__ int cnt[256];
    __shared__ int sc[256];
    __shared__ int ex[256];
    __shared__ int fill[256];
    __shared__ int stage[8192];
    int b = blockIdx.x;
    int t = threadIdx.x;
    int n0 = b << 8;
    int nn = min(256, N - n0);
    int base = bucket_base[b];
    int bcnt = ((b + 1 < nbuck) ? bucket_base[b + 1] : E) - base;

    cnt[t] = 0;
    fill[t] = 0;
    __syncthreads();
    // per-node counts
    for (int i = t; i < bcnt; i += 256)
        atomicAdd(&cnt[binned[base + i] & 255u], 1);
    __syncthreads();
    // 256-wide exclusive scan (Hillis-Steele)
    int v = cnt[t];
    sc[t] = v;
    __syncthreads();
    for (int off = 1; off < 256; off <<= 1) {
        int tv = (t >= off) ? sc[t - off] : 0;
        __syncthreads();
        sc[t] += tv;
        __syncthreads();
    }
    ex[t] = sc[t] - v;
    // rowptr + dinv
    if (t < nn) {
        rowptr[n0 + t] = base + ex[t];
        dinv[n0 + t] = rsqrtf((float)(1 + v));
    }
    if (b == nbuck - 1 && t == 0) rowptr[N] = E;
    __syncthreads();
    // rank + stage + coalesced write
    for (int i = t; i < bcnt; i += 256) {
        unsigned p = binned[base + i];
        int dl = (int)(p & 255u);
        int s = (int)(p >> 8);
        int pos = ex[dl] + atomicAdd(&fill[dl], 1);
        if (pos < 8192) stage[pos] = s;
        else csr_src[base + pos] = s;   // overflow fallback (~4.1k avg per bucket)
    }
    __syncthreads();
    int m = bcnt < 8192 ? bcnt : 8192;
    for (int i = t; i < m; i += 256) csr_src[base + i] = stage[i];
}

// ---------------- MFMA f16 GEMM: H = (X @ W) * dinv[row]  (f16 row-major out) ----

template <bool SRC_F16>
__global__ __launch_bounds__(256) void gemm_mfma_k(const void* __restrict__ Xv,
                                                   const _Float16* __restrict__ WT,
                                                   const float* __restrict__ dinvp,
                                                   _Float16* __restrict__ H, int nrows) {
    __shared__ uint4 ldsbuf[4096];  // 64 KB
    char* ldsA = (char*)ldsbuf;
    char* ldsB = (char*)ldsbuf + 32768;
    const int t = threadIdx.x;
    const int row0 = blockIdx.x * 128;

#pragma unroll
    for (int i = 0; i < 8; ++i) {
        int chunk = i * 256 + t;
        int r = chunk >> 4, cb = chunk & 15;
        half8 hv;
        if (row0 + r < nrows) {
            if (SRC_F16) {
                hv = *(const half8*)((const _Float16*)Xv + (size_t)(row0 + r) * NFEAT + cb * 8);
            } else {
                const float* X = (const float*)Xv;
                float4 v0 = *(const float4*)(X + (size_t)(row0 + r) * NFEAT + cb * 8);
                float4 v1 = *(const float4*)(X + (size_t)(row0 + r) * NFEAT + cb * 8 + 4);
                hv[0] = (_Float16)v0.x; hv[1] = (_Float16)v0.y;
                hv[2] = (_Float16)v0.z; hv[3] = (_Float16)v0.w;
                hv[4] = (_Float16)v1.x; hv[5] = (_Float16)v1.y;
                hv[6] = (_Float16)v1.z; hv[7] = (_Float16)v1.w;
            }
        } else {
            hv = (half8)(_Float16)0.f;
        }
        int byte = (r * 256 + cb * 16) ^ ((r & 7) << 4);
        *(half8*)(ldsA + byte) = hv;
    }
#pragma unroll
    for (int i = 0; i < 8; ++i) {
        int chunk = i * 256 + t;
        int r = chunk >> 4, cb = chunk & 15;
        half8 hv = *(const half8*)(WT + (size_t)r * NFEAT + cb * 8);
        int byte = (r * 256 + cb * 16) ^ ((r & 7) << 4);
        *(half8*)(ldsB + byte) = hv;
    }
    __syncthreads();

    const int w = t >> 6, lane = t & 63;
    const int wr = w >> 1, wc = w & 1;
    const int lrow = lane & 15, kgrp = lane >> 4;

    f32x4 acc[4][4];
#pragma unroll
    for (int m = 0; m < 4; ++m)
#pragma unroll
        for (int n = 0; n < 4; ++n) acc[m][n] = (f32x4)0.f;

#pragma unroll
    for (int kk = 0; kk < 4; ++kk) {
        int kb = (kk * 32 + kgrp * 8) * 2;
        half8 a[4], b[4];
#pragma unroll
        for (int m = 0; m < 4; ++m) {
            int r = wr * 64 + m * 16 + lrow;
            a[m] = *(const half8*)(ldsA + ((r * 256 + kb) ^ ((r & 7) << 4)));
        }
#pragma unroll
        for (int n = 0; n < 4; ++n) {
            int c = wc * 64 + n * 16 + lrow;
            b[n] = *(const half8*)(ldsB + ((c * 256 + kb) ^ ((c & 7) << 4)));
        }
#pragma unroll
        for (int m = 0; m < 4; ++m)
#pragma unroll
            for (int n = 0; n < 4; ++n)
                acc[m][n] = __builtin_amdgcn_mfma_f32_16x16x32_f16(a[m], b[n], acc[m][n], 0, 0, 0);
    }

#pragma unroll
    for (int m = 0; m < 4; ++m) {
#pragma unroll
        for (int j = 0; j < 4; ++j) {
            int row = row0 + wr * 64 + m * 16 + kgrp * 4 + j;
            if (row < nrows) {
                float sc = dinvp[row];
#pragma unroll
                for (int n = 0; n < 4; ++n)
                    H[(size_t)row * NFEAT + wc * 64 + n * 16 + lrow] =
                        (_Float16)(acc[m][n][j] * sc);
            }
        }
    }
}

// ---------------- CSR aggregation: one wave per node, 4 groups x 16 lanes ----
// 16-edge unroll: 4 half8 gathers (16B) in flight; packed f16 partials.

template <bool FINAL>
__global__ __launch_bounds__(256) void agg_csr_k(const int* __restrict__ rowptr,
                                                 const int* __restrict__ csr_src,
                                                 const float* __restrict__ dinv,
                                                 const _Float16* __restrict__ h,
                                                 const float* __restrict__ bias,
                                                 void* __restrict__ outv, int N) {
    int node = (int)((blockIdx.x * (unsigned)blockDim.x + threadIdx.x) >> 6);
    if (node >= N) return;
    int lane = threadIdx.x & 63;
    int g = lane >> 4;        // edge group 0..3
    int fl = lane & 15;       // feature block: feats fl*8 .. fl*8+7
    const _Float16* hfb = h + fl * 8;

    int p0 = rowptr[node], p1 = rowptr[node + 1];
    half8 ha0 = (half8)(_Float16)0.f, ha1 = ha0, ha2 = ha0, ha3 = ha0;

    int p = p0;
    for (; p + 16 <= p1; p += 16) {
        int s0 = csr_src[p + g];
        int s1 = csr_src[p + 4 + g];
        int s2 = csr_src[p + 8 + g];
        int s3 = csr_src[p + 12 + g];
        half8 v0 = *(const half8*)(hfb + (size_t)s0 * NFEAT);
        half8 v1 = *(const half8*)(hfb + (size_t)s1 * NFEAT);
        half8 v2 = *(const half8*)(hfb + (size_t)s2 * NFEAT);
        half8 v3 = *(const half8*)(hfb + (size_t)s3 * NFEAT);
        ha0 += v0; ha1 += v1; ha2 += v2; ha3 += v3;
    }
    if (p + 8 <= p1) {
        int s0 = csr_src[p + g];
        int s1 = csr_src[p + 4 + g];
        half8 v0 = *(const half8*)(hfb + (size_t)s0 * NFEAT);
        half8 v1 = *(const half8*)(hfb + (size_t)s1 * NFEAT);
        ha0 += v0; ha1 += v1;
        p += 8;
    }
    if (p + 4 <= p1) {
        int s0 = csr_src[p + g];
        half8 v0 = *(const half8*)(hfb + (size_t)s0 * NFEAT);
        ha2 += v0;
        p += 4;
    }
    if (p + g < p1) {
        int s0 = csr_src[p + g];
        half8 v0 = *(const half8*)(hfb + (size_t)s0 * NFEAT);
        ha3 += v0;
    }
    if (g == 0) {  // self-loop once
        half8 vs = *(const half8*)(hfb + (size_t)node * NFEAT);
        ha0 += vs;
    }
    ha0 += ha1;
    ha2 += ha3;
    ha0 += ha2;

    float acc[8];
#pragma unroll
    for (int i = 0; i < 8; ++i) acc[i] = (float)ha0[i];
#pragma unroll
    for (int i = 0; i < 8; ++i) {
        acc[i] += __shfl_xor(acc[i], 16, 64);
        acc[i] += __shfl_xor(acc[i], 32, 64);
    }
    if (g == 0) {
        float dd = dinv[node];
        float4 bv0 = *(const float4*)(bias + fl * 8);
        float4 bv1 = *(const float4*)(bias + fl * 8 + 4);
        float o[8];
        o[0] = fmaf(dd, acc[0], bv0.x); o[1] = fmaf(dd, acc[1], bv0.y);
        o[2] = fmaf(dd, acc[2], bv0.z); o[3] = fmaf(dd, acc[3], bv0.w);
        o[4] = fmaf(dd, acc[4], bv1.x); o[5] = fmaf(dd, acc[5], bv1.y);
        o[6] = fmaf(dd, acc[6], bv1.z); o[7] = fmaf(dd, acc[7], bv1.w);
        if (FINAL) {
            float* out = (float*)outv + (size_t)node * NFEAT + fl * 8;
            *(float4*)out = make_float4(o[0], o[1], o[2], o[3]);
            *(float4*)(out + 4) = make_float4(o[4], o[5], o[6], o[7]);
        } else {
            half8 ho;
#pragma unroll
            for (int i = 0; i < 8; ++i) ho[i] = (_Float16)fmaxf(o[i], 0.f);
            *(half8*)((_Float16*)outv + (size_t)node * NFEAT + fl * 8) = ho;
        }
    }
}

// ---------------- launch ----------------

extern "C" void kernel_launch(void* const* d_in, const int* in_sizes, int n_in,
                              void* d_out, int out_size, void* d_ws, size_t ws_size,
                              hipStream_t stream) {
    const float* x  = (const float*)d_in[0];
    const int*   ei = (const int*)d_in[1];
    const float* W1 = (const float*)d_in[2];
    const float* b1 = (const float*)d_in[3];
    const float* W2 = (const float*)d_in[4];
    const float* b2 = (const float*)d_in[5];
    float* out = (float*)d_out;

    const int N = in_sizes[0] / NFEAT;
    const int E = in_sizes[1] / 2;
    const int* srcv = ei;
    const int* dstv = ei + E;

    char* wsp = (char*)d_ws;
    size_t off = 0;
    auto alloc = [&](size_t bytes) {
        char* p = wsp + off;
        off = (off + bytes + 255) & ~(size_t)255;
        return p;
    };
    float*    dinv     = (float*)alloc((size_t)N * 4);
    int*      rowptr   = (int*)alloc((size_t)(N + 1) * 4);
    int*      gcount   = (int*)alloc(MAXBUCK * 4);
    int*      bbase    = (int*)alloc(MAXBUCK * 4);
    int*      bfill    = (int*)alloc(MAXBUCK * 4);
    int*      csr_src  = (int*)alloc((size_t)E * 4);
    _Float16* wt1      = (_Float16*)alloc(NFEAT * NFEAT * 2);
    _Float16* wt2      = (_Float16*)alloc(NFEAT * NFEAT * 2);
    _Float16* hbuf     = (_Float16*)alloc((size_t)N * NFEAT * 2);
    _Float16* a1buf    = (_Float16*)alloc((size_t)N * NFEAT * 2);
    unsigned* binned   = (unsigned*)hbuf;  // alias: consumed by binB2 before gemm1

    const int nbuck = (N + 255) >> 8;          // 391
    const int nchunk = (E + CHUNK - 1) / CHUNK;

    // build: prep -> bucket hist -> bucket scan -> binA2 -> binB2 (rowptr+dinv+sort)
    prep_k<<<64, 256, 0, stream>>>(gcount, nbuck, W1, W2, wt1, wt2);
    bhist_k<<<nchunk, 256, 0, stream>>>(dstv, E, gcount, nbuck);
    bscan_k<<<1, 512, 0, stream>>>(gcount, bbase, bfill, nbuck);
    binA2_k<<<nchunk, 256, 0, stream>>>(srcv, dstv, bbase, bfill, binned, E, nbuck);
    binB2_k<<<nbuck, 256, 0, stream>>>(binned, bbase, rowptr, dinv, csr_src, N, E, nbuck);

    const int gemm_blocks = (N + 127) / 128;
    const int agg_blocks = (int)(((size_t)N * 64 + 255) / 256);

    // layer 1: h1' = (x@W1)*dinv ; a1 = relu(dinv*Agg(h1') + b1) (f16)
    gemm_mfma_k<false><<<gemm_blocks, 256, 0, stream>>>(x, wt1, dinv, hbuf, N);
    agg_csr_k<false><<<agg_blocks, 256, 0, stream>>>(rowptr, csr_src, dinv, hbuf, b1, a1buf, N);

    // layer 2: h2' = (a1@W2)*dinv ; out = dinv*Agg(h2') + b2 (fp32)
    gemm_mfma_k<true><<<gemm_blocks, 256, 0, stream>>>(a1buf, wt2, dinv, hbuf, N);
    agg_csr_k<true><<<agg_blocks, 256, 0, stream>>>(rowptr, csr_src, dinv, hbuf, b2, out, N);
}